// Round 3
// baseline (23.591 us; speedup 1.0000x reference)
//
#include <hip/hip_runtime.h>

#define N_ANCHORS 100000
#define BATCH 4
#define N_GT 64
#define GT_SPLIT 2
#define GT_PER (N_GT / GT_SPLIT)   // 32 gt boxes per thread

__global__ __launch_bounds__(256) void max_iou_kernel(
    const float4* __restrict__ anchors,
    const float4* __restrict__ gt,
    unsigned int* __restrict__ out)
{
    const int i = blockIdx.x * blockDim.x + threadIdx.x;
    const int b = blockIdx.y;
    const int z = blockIdx.z;
    if (i >= N_ANCHORS) return;

    const float4 a = anchors[i];
    const float a_area = (a.z - a.x) * (a.w - a.y);

    const float4* gtb = gt + b * N_GT + z * GT_PER;

    // Two independent accumulator streams; iou >= 0 so 0 is the max identity.
    float m0 = 0.0f, m1 = 0.0f;

    #pragma unroll
    for (int g = 0; g < GT_PER; g += 2) {
        {
            const float4 gb = gtb[g];          // uniform -> scalar load
            const float ix1 = fmaxf(a.x, gb.x);
            const float iy1 = fmaxf(a.y, gb.y);
            const float ix2 = fminf(a.z, gb.z);
            const float iy2 = fminf(a.w, gb.w);
            const float iw = fmaxf(ix2 - ix1, 0.0f);
            const float ih = fmaxf(iy2 - iy1, 0.0f);
            const float inter = iw * ih;
            const float g_area = (gb.z - gb.x) * (gb.w - gb.y);
            const float uni = a_area + g_area - inter;
            // union > 0 always (all boxes have positive area); inter==0 -> iou 0.
            m0 = fmaxf(m0, inter * __builtin_amdgcn_rcpf(uni));
        }
        {
            const float4 gb = gtb[g + 1];
            const float ix1 = fmaxf(a.x, gb.x);
            const float iy1 = fmaxf(a.y, gb.y);
            const float ix2 = fminf(a.z, gb.z);
            const float iy2 = fminf(a.w, gb.w);
            const float iw = fmaxf(ix2 - ix1, 0.0f);
            const float ih = fmaxf(iy2 - iy1, 0.0f);
            const float inter = iw * ih;
            const float g_area = (gb.z - gb.x) * (gb.w - gb.y);
            const float uni = a_area + g_area - inter;
            m1 = fmaxf(m1, inter * __builtin_amdgcn_rcpf(uni));
        }
    }

    const float m = fmaxf(m0, m1);
    // iou >= 0 => float ordering == unsigned ordering on the bit patterns.
    atomicMax(&out[b * N_ANCHORS + i], __float_as_uint(m));
}

extern "C" void kernel_launch(void* const* d_in, const int* in_sizes, int n_in,
                              void* d_out, int out_size, void* d_ws, size_t ws_size,
                              hipStream_t stream) {
    const float4* anchors = (const float4*)d_in[0];  // (100000, 4) fp32
    const float4* gt      = (const float4*)d_in[1];  // (4, 64, 4) fp32
    unsigned int* out     = (unsigned int*)d_out;    // (4, 100000) fp32 bits

    // Zero the output so atomic umax accumulates from 0.0f (graph memset node).
    hipMemsetAsync(out, 0, (size_t)out_size * sizeof(float), stream);

    dim3 grid((N_ANCHORS + 255) / 256, BATCH, GT_SPLIT);
    max_iou_kernel<<<grid, 256, 0, stream>>>(anchors, gt, out);
}

// Round 4
// 20.331 us; speedup vs baseline: 1.1603x; 1.1603x over previous
//
#include <hip/hip_runtime.h>

#define N_ANCHORS 100000
#define BATCH 4
#define N_GT 64

__global__ __launch_bounds__(256) void max_iou_kernel(
    const float4* __restrict__ anchors,
    const float4* __restrict__ gt,
    float* __restrict__ out)
{
    // Stage this batch's 64 gt boxes + precomputed areas in LDS (1.25 KB).
    __shared__ float4 s_box[N_GT];
    __shared__ float  s_area[N_GT];

    const int tid = threadIdx.x;
    const int b = blockIdx.y;

    if (tid < N_GT) {
        const float4 g = gt[b * N_GT + tid];
        s_box[tid] = g;
        s_area[tid] = (g.z - g.x) * (g.w - g.y);
    }
    __syncthreads();

    const int i = blockIdx.x * blockDim.x + tid;
    if (i >= N_ANCHORS) return;

    const float4 a = anchors[i];
    const float a_area = (a.z - a.x) * (a.w - a.y);

    // 4 independent running maxima -> no serial fmax dependency chain.
    float m0 = 0.0f, m1 = 0.0f, m2 = 0.0f, m3 = 0.0f;

    #pragma unroll
    for (int g = 0; g < N_GT; g += 4) {
        {
            const float4 gb = s_box[g + 0];          // uniform addr -> broadcast
            const float iw = fmaxf(fminf(a.z, gb.z) - fmaxf(a.x, gb.x), 0.0f);
            const float ih = fmaxf(fminf(a.w, gb.w) - fmaxf(a.y, gb.y), 0.0f);
            const float inter = iw * ih;
            const float uni = (a_area + s_area[g + 0]) - inter;  // > 0 always
            m0 = fmaxf(m0, inter * __builtin_amdgcn_rcpf(uni));  // 0 if inter==0
        }
        {
            const float4 gb = s_box[g + 1];
            const float iw = fmaxf(fminf(a.z, gb.z) - fmaxf(a.x, gb.x), 0.0f);
            const float ih = fmaxf(fminf(a.w, gb.w) - fmaxf(a.y, gb.y), 0.0f);
            const float inter = iw * ih;
            const float uni = (a_area + s_area[g + 1]) - inter;
            m1 = fmaxf(m1, inter * __builtin_amdgcn_rcpf(uni));
        }
        {
            const float4 gb = s_box[g + 2];
            const float iw = fmaxf(fminf(a.z, gb.z) - fmaxf(a.x, gb.x), 0.0f);
            const float ih = fmaxf(fminf(a.w, gb.w) - fmaxf(a.y, gb.y), 0.0f);
            const float inter = iw * ih;
            const float uni = (a_area + s_area[g + 2]) - inter;
            m2 = fmaxf(m2, inter * __builtin_amdgcn_rcpf(uni));
        }
        {
            const float4 gb = s_box[g + 3];
            const float iw = fmaxf(fminf(a.z, gb.z) - fmaxf(a.x, gb.x), 0.0f);
            const float ih = fmaxf(fminf(a.w, gb.w) - fmaxf(a.y, gb.y), 0.0f);
            const float inter = iw * ih;
            const float uni = (a_area + s_area[g + 3]) - inter;
            m3 = fmaxf(m3, inter * __builtin_amdgcn_rcpf(uni));
        }
    }

    out[b * N_ANCHORS + i] = fmaxf(fmaxf(m0, m1), fmaxf(m2, m3));
}

extern "C" void kernel_launch(void* const* d_in, const int* in_sizes, int n_in,
                              void* d_out, int out_size, void* d_ws, size_t ws_size,
                              hipStream_t stream) {
    const float4* anchors = (const float4*)d_in[0];  // (100000, 4) fp32
    const float4* gt      = (const float4*)d_in[1];  // (4, 64, 4) fp32
    float* out            = (float*)d_out;           // (4, 100000) fp32

    dim3 grid((N_ANCHORS + 255) / 256, BATCH);
    max_iou_kernel<<<grid, 256, 0, stream>>>(anchors, gt, out);
}

// Round 5
// 19.441 us; speedup vs baseline: 1.2134x; 1.0458x over previous
//
#include <hip/hip_runtime.h>

#define N_ANCHORS 100000
#define BATCH 4
#define N_GT 64
#define PAIRS ((N_ANCHORS + 1) / 2)

__global__ __launch_bounds__(256) void max_iou_kernel(
    const float4* __restrict__ anchors,
    const float4* __restrict__ gt,
    float* __restrict__ out)
{
    // Stage this batch's 64 gt boxes in LDS (1 KB). Areas recomputed in VALU
    // (3 ops) to keep LDS-pipe traffic at one ds_read_b128 per gt per thread.
    __shared__ float4 s_box[N_GT];

    const int tid = threadIdx.x;
    const int b = blockIdx.y;

    if (tid < N_GT) s_box[tid] = gt[b * N_GT + tid];
    __syncthreads();

    const int p = blockIdx.x * blockDim.x + tid;   // anchor pair index
    const int i0 = 2 * p;
    if (i0 >= N_ANCHORS) return;                   // N even -> pairs never split

    const float4 a0 = anchors[i0];
    const float4 a1 = anchors[i0 + 1];
    const float area0 = (a0.z - a0.x) * (a0.w - a0.y);
    const float area1 = (a1.z - a1.x) * (a1.w - a1.y);

    // 2 anchors x 2 max streams = 4 independent dependency chains.
    float m00 = 0.0f, m01 = 0.0f, m10 = 0.0f, m11 = 0.0f;

    #pragma unroll
    for (int g = 0; g < N_GT; g += 2) {
        {
            const float4 gb = s_box[g + 0];                    // broadcast b128
            const float ga = (gb.z - gb.x) * (gb.w - gb.y);    // g_area in VALU
            {
                float iw = fminf(a0.z, gb.z) - fmaxf(a0.x, gb.x);
                float ih = fminf(a0.w, gb.w) - fmaxf(a0.y, gb.y);
                iw = fmaxf(iw, 0.0f); ih = fmaxf(ih, 0.0f);
                const float inter = iw * ih;
                const float uni = (area0 + ga) - inter;        // > 0 always
                m00 = fmaxf(m00, inter * __builtin_amdgcn_rcpf(uni));
            }
            {
                float iw = fminf(a1.z, gb.z) - fmaxf(a1.x, gb.x);
                float ih = fminf(a1.w, gb.w) - fmaxf(a1.y, gb.y);
                iw = fmaxf(iw, 0.0f); ih = fmaxf(ih, 0.0f);
                const float inter = iw * ih;
                const float uni = (area1 + ga) - inter;
                m10 = fmaxf(m10, inter * __builtin_amdgcn_rcpf(uni));
            }
        }
        {
            const float4 gb = s_box[g + 1];
            const float ga = (gb.z - gb.x) * (gb.w - gb.y);
            {
                float iw = fminf(a0.z, gb.z) - fmaxf(a0.x, gb.x);
                float ih = fminf(a0.w, gb.w) - fmaxf(a0.y, gb.y);
                iw = fmaxf(iw, 0.0f); ih = fmaxf(ih, 0.0f);
                const float inter = iw * ih;
                const float uni = (area0 + ga) - inter;
                m01 = fmaxf(m01, inter * __builtin_amdgcn_rcpf(uni));
            }
            {
                float iw = fminf(a1.z, gb.z) - fmaxf(a1.x, gb.x);
                float ih = fminf(a1.w, gb.w) - fmaxf(a1.y, gb.y);
                iw = fmaxf(iw, 0.0f); ih = fmaxf(ih, 0.0f);
                const float inter = iw * ih;
                const float uni = (area1 + ga) - inter;
                m11 = fmaxf(m11, inter * __builtin_amdgcn_rcpf(uni));
            }
        }
    }

    float2 r;
    r.x = fmaxf(m00, m01);
    r.y = fmaxf(m10, m11);
    *reinterpret_cast<float2*>(&out[b * N_ANCHORS + i0]) = r;   // 8B coalesced
}

extern "C" void kernel_launch(void* const* d_in, const int* in_sizes, int n_in,
                              void* d_out, int out_size, void* d_ws, size_t ws_size,
                              hipStream_t stream) {
    const float4* anchors = (const float4*)d_in[0];  // (100000, 4) fp32
    const float4* gt      = (const float4*)d_in[1];  // (4, 64, 4) fp32
    float* out            = (float*)d_out;           // (4, 100000) fp32

    dim3 grid((PAIRS + 255) / 256, BATCH);
    max_iou_kernel<<<grid, 256, 0, stream>>>(anchors, gt, out);
}

// Round 6
// 18.808 us; speedup vs baseline: 1.2543x; 1.0336x over previous
//
#include <hip/hip_runtime.h>

#define N_ANCHORS 100000
#define BATCH 4
#define N_GT 64
#define PAIRS (N_ANCHORS / 2)   // N even -> 50000 pairs, never split

__global__ __launch_bounds__(256) void max_iou_kernel(
    const float4* __restrict__ anchors,
    const float4* __restrict__ gt,
    float* __restrict__ out)
{
    // gt boxes staged as (-x1, -y1, x2, y2) + area: iw = min(az,gz)+min(-ax,-gx).
    __shared__ float4 s_neg[N_GT];
    __shared__ float  s_ga[N_GT];

    const int tid = threadIdx.x;
    const int b = blockIdx.y;

    if (tid < N_GT) {
        const float4 g = gt[b * N_GT + tid];
        s_neg[tid] = make_float4(-g.x, -g.y, g.z, g.w);
        s_ga[tid]  = (g.z - g.x) * (g.w - g.y);
    }
    __syncthreads();

    const int p = blockIdx.x * blockDim.x + tid;
    const int i0 = 2 * p;
    if (i0 >= N_ANCHORS) return;

    const float4 a0 = anchors[i0];
    const float4 a1 = anchors[i0 + 1];
    const float area0 = (a0.z - a0.x) * (a0.w - a0.y);
    const float area1 = (a1.z - a1.x) * (a1.w - a1.y);
    const float a0xn = -a0.x, a0yn = -a0.y;
    const float a1xn = -a1.x, a1yn = -a1.y;

    // Track t = inter / (areaA + areaG).  iou = t/(1-t) is monotone in t,
    // so max-iou == max-t converted once at the end.  t in [0, 1/2].
    float t0 = 0.0f, t1 = 0.0f;

    #pragma unroll 8
    for (int g = 0; g < N_GT; ++g) {
        const float4 gb = s_neg[g];      // (-gx1, -gy1, gx2, gy2), broadcast b128
        const float ga  = s_ga[g];       // broadcast b32
        const float r0  = __builtin_amdgcn_rcpf(area0 + ga);   // indep of inter
        const float r1  = __builtin_amdgcn_rcpf(area1 + ga);
        {
            // iw = min(az,gz) - max(ax,gx) = min(az,gz) + min(-ax,-gx)
            const float iw = fmaxf(fminf(a0.z, gb.z) + fminf(a0xn, gb.x), 0.0f);
            const float ih = fminf(a0.w, gb.w) + fminf(a0yn, gb.y);
            // ih < 0 -> t <= 0 -> discarded by fmax (t0 >= 0): clamp not needed.
            t0 = fmaxf(t0, iw * ih * r0);
        }
        {
            const float iw = fmaxf(fminf(a1.z, gb.z) + fminf(a1xn, gb.x), 0.0f);
            const float ih = fminf(a1.w, gb.w) + fminf(a1yn, gb.y);
            t1 = fmaxf(t1, iw * ih * r1);
        }
    }

    // iou = T / (1 - T); T <= 1/2 so 1-T >= 1/2 (rcp well-conditioned); T=0 -> 0.
    float2 r;
    r.x = t0 * __builtin_amdgcn_rcpf(1.0f - t0);
    r.y = t1 * __builtin_amdgcn_rcpf(1.0f - t1);
    *reinterpret_cast<float2*>(&out[b * N_ANCHORS + i0]) = r;
}

extern "C" void kernel_launch(void* const* d_in, const int* in_sizes, int n_in,
                              void* d_out, int out_size, void* d_ws, size_t ws_size,
                              hipStream_t stream) {
    const float4* anchors = (const float4*)d_in[0];  // (100000, 4) fp32
    const float4* gt      = (const float4*)d_in[1];  // (4, 64, 4) fp32
    float* out            = (float*)d_out;           // (4, 100000) fp32

    dim3 grid((PAIRS + 255) / 256, BATCH);
    max_iou_kernel<<<grid, 256, 0, stream>>>(anchors, gt, out);
}

// Round 7
// 18.458 us; speedup vs baseline: 1.2780x; 1.0190x over previous
//
#include <hip/hip_runtime.h>

#define N_ANCHORS 100000
#define BATCH 4
#define N_GT 64
#define PAIRS (N_ANCHORS / 2)   // N even -> pairs never split

typedef float v2f __attribute__((ext_vector_type(2)));

__global__ __launch_bounds__(256) void max_iou_kernel(
    const float4* __restrict__ anchors,
    const float4* __restrict__ gt,
    float* __restrict__ out)
{
    // gt staged as (-x1, -y1, x2, y2) + area.
    __shared__ float4 s_neg[N_GT];
    __shared__ float  s_ga[N_GT];

    const int tid = threadIdx.x;
    const int b = blockIdx.y;

    if (tid < N_GT) {
        const float4 g = gt[b * N_GT + tid];
        s_neg[tid] = make_float4(-g.x, -g.y, g.z, g.w);
        s_ga[tid]  = (g.z - g.x) * (g.w - g.y);
    }
    __syncthreads();

    const int p = blockIdx.x * blockDim.x + tid;
    const int i0 = 2 * p;
    if (i0 >= N_ANCHORS) return;

    const float4 a0 = anchors[i0];
    const float4 a1 = anchors[i0 + 1];

    // Anchor pair in packed registers; x1/y1 pre-negated so every subtract
    // becomes an add (v_pk_add_f32 pairs them; min/max have no packed form).
    const v2f az  = {a0.z, a1.z};
    const v2f aw  = {a0.w, a1.w};
    const v2f axn = {-a0.x, -a1.x};
    const v2f ayn = {-a0.y, -a1.y};
    const v2f area = (az + axn) * (aw + ayn);          // pk_add x2, pk_mul

    // Track t = inter / (areaA + areaG); iou = t/(1-t) monotone in t.
    v2f t = {0.0f, 0.0f};

    #pragma unroll 8
    for (int g = 0; g < N_GT; ++g) {
        const float4 gb = s_neg[g];        // broadcast b128: (-gx1,-gy1,gx2,gy2)
        const float ga  = s_ga[g];         // broadcast b32
        const v2f S = area + ga;                        // pk_add (splat)
        v2f r;
        r.x = __builtin_amdgcn_rcpf(S.x);               // indep of inter -> hides
        r.y = __builtin_amdgcn_rcpf(S.y);
        const v2f gz = {gb.z, gb.z}, gxn = {gb.x, gb.x};
        const v2f gw = {gb.w, gb.w}, gyn = {gb.y, gb.y};
        // iw = min(az,gz) - max(ax,gx) = min(az,gz) + min(-ax,-gx)
        const v2f iw0 = __builtin_elementwise_min(az, gz)
                      + __builtin_elementwise_min(axn, gxn);   // pk_add
        const v2f ih  = __builtin_elementwise_min(aw, gw)
                      + __builtin_elementwise_min(ayn, gyn);   // pk_add
        const v2f iw  = __builtin_elementwise_max(iw0, (v2f){0.0f, 0.0f});
        // ih < 0 -> t_cand <= 0 -> discarded by the max (t >= 0): no ih clamp.
        t = __builtin_elementwise_max(t, iw * ih * r);         // pk_mul x2
    }

    // iou = t/(1-t); t <= 1/2 so 1-t >= 1/2 (well-conditioned); t=0 -> 0.
    v2f invd;
    invd.x = __builtin_amdgcn_rcpf(1.0f - t.x);
    invd.y = __builtin_amdgcn_rcpf(1.0f - t.y);
    const v2f iou = t * invd;

    float2 res;
    res.x = iou.x;
    res.y = iou.y;
    *reinterpret_cast<float2*>(&out[b * N_ANCHORS + i0]) = res;   // 8B coalesced
}

extern "C" void kernel_launch(void* const* d_in, const int* in_sizes, int n_in,
                              void* d_out, int out_size, void* d_ws, size_t ws_size,
                              hipStream_t stream) {
    const float4* anchors = (const float4*)d_in[0];  // (100000, 4) fp32
    const float4* gt      = (const float4*)d_in[1];  // (4, 64, 4) fp32
    float* out            = (float*)d_out;           // (4, 100000) fp32

    dim3 grid((PAIRS + 255) / 256, BATCH);
    max_iou_kernel<<<grid, 256, 0, stream>>>(anchors, gt, out);
}